// Round 13
// baseline (78.288 us; speedup 1.0000x reference)
//
#include <hip/hip_runtime.h>
#include <math.h>

#define KK 20
#define NPTS 8192
#define NQB 8               // queries per block
#define QPL 4               // queries per lane (2 groups x 4)
#define NCH 256             // chunks per query (32 pts: 4 window-groups x 8)
#define THREADS 512
#define WIN 2048
#define NWIN 4
#define JPW 8               // consecutive points per chunk per window-group
#define CAP 64              // hit buffer capacity per query
#define MAXC 64             // candidate-chunk list capacity per query
#define MARGIN 4e-3f        // >> 2*max|d_fast - d_exact|

// Exact (non-contracted) IEEE ops matching the NumPy reference bit-for-bit.
// np.sum (pairwise, n<8) accumulates ascending: (x^2 + y^2) + z^2.
__device__ __forceinline__ float norm3(float x, float y, float z) {
    return __fadd_rn(__fadd_rn(__fmul_rn(x, x), __fmul_rn(y, y)), __fmul_rn(z, z));
}

// np.einsum (optimize=False) remainder falls through DESCENDING for count=3:
// ((z*z') + y*y') + x*x'.  dist = ((-2*dot) + n_src) + n_dst.
__device__ __forceinline__ float dist_exact(float px, float py, float pz, float pw,
                                            float qx, float qy, float qz, float qn) {
    const float dot = __fadd_rn(
        __fadd_rn(__fmul_rn(pz, qz), __fmul_rn(py, qy)), __fmul_rn(px, qx));
    return __fadd_rn(__fadd_rn(__fmul_rn(dot, -2.0f), pw), qn);
}

extern "C" __global__ __launch_bounds__(THREADS, 8)
void knn_kernel(const float* __restrict__ verts, int* __restrict__ out)
{
    // LDS ~17.5 KB -> 4 blocks/CU (2048 threads/CU = HW max).
    __shared__ float vdump[NCH][NQB + 1];       // 9216 B
    __shared__ float hbd[NQB][CAP];             // 2048 B
    __shared__ int   hbi[NQB][CAP];             // 2048 B
    __shared__ int   cand[NQB][MAXC];           // 2048 B
    __shared__ float Tq[NQB];
    __shared__ int   cnt[NQB];
    __shared__ int   cnt2[NQB];

    const int t    = threadIdx.x;
    const int lane = t & 63;
    const int wv   = t >> 6;          // wave 0..7  (= its query)
    const int c    = t >> 1;          // chunk 0..255
    const int qh   = t & 1;           // query group 0..1
    const int qbase = blockIdx.x * NQB + qh * QPL;

    if (t < NQB) { cnt[t] = 0; cnt2[t] = 0; }

    // Register tile: 4 queries per lane. Fast path: folded -2*q coords, qn
    // omitted inside the min (constant per query, re-added once).
    float qx2[QPL], qy2[QPL], qz2[QPL], qn[QPL];
#pragma unroll
    for (int i = 0; i < QPL; ++i) {
        const float x = verts[(qbase + i) * 3 + 0];
        const float y = verts[(qbase + i) * 3 + 1];
        const float z = verts[(qbase + i) * 3 + 2];
        qn[i] = norm3(x, y, z);
        qx2[i] = -2.0f * x; qy2[i] = -2.0f * y; qz2[i] = -2.0f * z;
    }

    // ---------------- PASS 1: per-(chunk,query) MIN, straight from global ---
    // Chunk c = { w*WIN + c*8 + j : w<4, j<8 }. Each (w): 24 consecutive
    // floats = 6 aligned float4 loads (byte offset 96*(...) % 16 == 0).
    float mn[QPL];
#pragma unroll
    for (int i = 0; i < QPL; ++i) mn[i] = INFINITY;

    auto pair4 = [&](float px, float py, float pz) {
        const float pw = norm3(px, py, pz);
#pragma unroll
        for (int i = 0; i < QPL; ++i) {
            const float d = __builtin_fmaf(px, qx2[i],
                            __builtin_fmaf(py, qy2[i],
                            __builtin_fmaf(pz, qz2[i], pw)));
            mn[i] = fminf(mn[i], d);
        }
    };

#pragma unroll
    for (int w = 0; w < NWIN; ++w) {
        const float4* vp = (const float4*)(verts + (w * WIN + c * JPW) * 3);
        {   // points 0..3
            const float4 A = vp[0], B = vp[1], C = vp[2];
            pair4(A.x, A.y, A.z); pair4(A.w, B.x, B.y);
            pair4(B.z, B.w, C.x); pair4(C.y, C.z, C.w);
        }
        {   // points 4..7
            const float4 A = vp[3], B = vp[4], C = vp[5];
            pair4(A.x, A.y, A.z); pair4(A.w, B.x, B.y);
            pair4(B.z, B.w, C.x); pair4(C.y, C.z, C.w);
        }
    }

    // Re-add qn so vdump holds true fast distances.
#pragma unroll
    for (int i = 0; i < QPL; ++i) {
        mn[i] += qn[i];
        vdump[c][qh * QPL + i] = mn[i];
    }
    __syncthreads();

    // ------- T' = 20th smallest of 256 chunk-minima + margin ----------------
    // Wave wv handles query wv: 256-elem bitonic, 4 regs/lane (elem = lane*4+reg).
    {
        const int qq = wv;
        float r0 = vdump[lane * 4 + 0][qq];
        float r1 = vdump[lane * 4 + 1][qq];
        float r2 = vdump[lane * 4 + 2][qq];
        float r3 = vdump[lane * 4 + 3][qq];
        { const float lo = fminf(r0, r1), hi = fmaxf(r0, r1); r0 = lo; r1 = hi; }
        { const float lo = fminf(r2, r3), hi = fmaxf(r2, r3); r2 = hi; r3 = lo; }
#pragma unroll
        for (int k = 4; k <= 256; k <<= 1) {
            const bool asc = (((lane << 2) & k) == 0);
#pragma unroll
            for (int j = k >> 1; j >= 4; j >>= 1) {
                const int lj = j >> 2;
                const bool lower = ((lane & lj) == 0);
                const bool keepmin = (lower == asc);
                const float o0 = __shfl_xor(r0, lj), o1 = __shfl_xor(r1, lj);
                const float o2 = __shfl_xor(r2, lj), o3 = __shfl_xor(r3, lj);
                r0 = keepmin ? fminf(r0, o0) : fmaxf(r0, o0);
                r1 = keepmin ? fminf(r1, o1) : fmaxf(r1, o1);
                r2 = keepmin ? fminf(r2, o2) : fmaxf(r2, o2);
                r3 = keepmin ? fminf(r3, o3) : fmaxf(r3, o3);
            }
            {   // j = 2
                const float lo0 = fminf(r0, r2), hi0 = fmaxf(r0, r2);
                const float lo1 = fminf(r1, r3), hi1 = fmaxf(r1, r3);
                r0 = asc ? lo0 : hi0; r2 = asc ? hi0 : lo0;
                r1 = asc ? lo1 : hi1; r3 = asc ? hi1 : lo1;
            }
            {   // j = 1
                const float lo0 = fminf(r0, r1), hi0 = fmaxf(r0, r1);
                const float lo1 = fminf(r2, r3), hi1 = fmaxf(r2, r3);
                r0 = asc ? lo0 : hi0; r1 = asc ? hi0 : lo0;
                r2 = asc ? lo1 : hi1; r3 = asc ? hi1 : lo1;
            }
        }
        const float T = __shfl(r3, 4);          // element 19 = lane 4, reg 3
        if (lane == 0) Tq[qq] = T + MARGIN;
    }
    __syncthreads();

    // ------- Candidate chunks ------------------------------------------------
#pragma unroll
    for (int i = 0; i < QPL; ++i) {
        const int q = qh * QPL + i;
        if (mn[i] <= Tq[q]) {
            const int e = atomicAdd(&cnt2[q], 1);
            if (e < MAXC) cand[q][e] = c;
        }
    }
    __syncthreads();

    // ------- PASS 2 (sparse): wave wv -> query wv, 2 cands/step, 4-deep -----
    // Half-wave half = lane>>5 takes cand e0+2u+half; p = lane&31 maps to
    // point n = (p>>3)*WIN + cc*JPW + (p&7)  (the chunk's true point set).
    {
        const int qq = wv;
        const int qg2 = blockIdx.x * NQB + qq;
        const float qxe = verts[qg2 * 3 + 0];
        const float qye = verts[qg2 * 3 + 1];
        const float qze = verts[qg2 * 3 + 2];
        const float qne = norm3(qxe, qye, qze);
        const float T = Tq[qq];
        const int nc = min(cnt2[qq], MAXC);
        const int half = lane >> 5;
        const int p = lane & 31;
        const int nfix = (p >> 3) * WIN + (p & 7);
        for (int e0 = 0; e0 < nc; e0 += 8) {    // wave-uniform, 8 cands/iter
            float PX[4], PY[4], PZ[4]; int NN[4];
#pragma unroll
            for (int u = 0; u < 4; ++u) {       // 12 independent loads in flight
                const int e = e0 + 2 * u + half;
                const int cc = cand[qq][e < nc ? e : 0];
                const int n = nfix + cc * JPW;
                NN[u] = n;
                PX[u] = verts[n * 3 + 0];
                PY[u] = verts[n * 3 + 1];
                PZ[u] = verts[n * 3 + 2];
            }
#pragma unroll
            for (int u = 0; u < 4; ++u) {
                if (e0 + 2 * u + half < nc) {
                    const float pw = norm3(PX[u], PY[u], PZ[u]);
                    const float d = dist_exact(PX[u], PY[u], PZ[u], pw,
                                               qxe, qye, qze, qne);
                    if (d <= T) {               // ~25 hits/query total
                        const int slot = atomicAdd(&cnt[qq], 1);
                        if (slot < CAP) { hbd[qq][slot] = d; hbi[qq][slot] = NN[u]; }
                    }
                }
            }
        }
    }
    __syncthreads();

    // ------- Final: exact stable top-20 via u64 bitonic (query wv) ----------
    {
        const int qq = wv;
        const int kc = min(cnt[qq], CAP);       // kc >= 20 guaranteed
        unsigned long long key = ~0ULL;
        if (lane < kc) {
            const float d = hbd[qq][lane];
            unsigned u = __float_as_uint(d);
            u ^= ((unsigned)((int)u >> 31)) | 0x80000000u;   // order-preserving map
            key = ((unsigned long long)u << 32) | (unsigned)hbi[qq][lane];
        }
#pragma unroll
        for (int k = 2; k <= 64; k <<= 1) {
#pragma unroll
            for (int j = k >> 1; j >= 1; j >>= 1) {
                const unsigned long long o = __shfl_xor(key, j);
                const bool asc = ((lane & k) == 0);
                const bool lower = ((lane & j) == 0);
                const bool keepmin = (lower == asc);
                const bool lt = key < o;
                key = (keepmin == lt) ? key : o;
            }
        }
        if (lane < KK)
            out[(blockIdx.x * NQB + qq) * KK + lane] =
                (int)(unsigned)(key & 0xffffffffULL);
    }
}

extern "C" void kernel_launch(void* const* d_in, const int* in_sizes, int n_in,
                              void* d_out, int out_size, void* d_ws, size_t ws_size,
                              hipStream_t stream) {
    // d_in[0] = feats (unused). d_in[1] = vertices [4,8192,3] f32; batch 0 only.
    const float* verts = (const float*)d_in[1];
    int* out = (int*)d_out;
    knn_kernel<<<dim3(NPTS / NQB), dim3(THREADS), 0, stream>>>(verts, out);
}

// Round 14
// 37.919 us; speedup vs baseline: 2.0646x; 2.0646x over previous
//
#include <hip/hip_runtime.h>
#include <math.h>

#define KK 20
#define NPTS 8192
#define NQB 16              // queries per block
#define QPL 8               // queries per lane (pass 1)
#define NCH 256             // chunks per query (32 pts each, strided across windows)
#define THREADS 512
#define WIN 2048            // points per staged LDS window
#define NWIN 4
#define JPW (WIN / NCH)     // 8 candidates per chunk per window
#define CAP 64              // hit buffer capacity per query
#define MAXC 64             // candidate-chunk list capacity per query
#define MARGIN 4e-3f        // >> 2*max|d_fast - d_exact|

// Exact (non-contracted) IEEE ops matching the NumPy reference bit-for-bit.
// np.sum (pairwise, n<8) accumulates ascending: (x^2 + y^2) + z^2.
__device__ __forceinline__ float norm3(float x, float y, float z) {
    return __fadd_rn(__fadd_rn(__fmul_rn(x, x), __fmul_rn(y, y)), __fmul_rn(z, z));
}

// np.einsum (optimize=False) remainder falls through DESCENDING for count=3:
// ((z*z') + y*y') + x*x'.  dist = ((-2*dot) + n_src) + n_dst.
__device__ __forceinline__ float dist_exact(float px, float py, float pz, float pw,
                                            float qx, float qy, float qz, float qn) {
    const float dot = __fadd_rn(
        __fadd_rn(__fmul_rn(pz, qz), __fmul_rn(py, qy)), __fmul_rn(px, qx));
    return __fadd_rn(__fadd_rn(__fmul_rn(dot, -2.0f), pw), qn);
}

// ---- prep: ws[n] = float4(x, y, z, norm) for batch-0 points -----------------
extern "C" __global__ __launch_bounds__(256)
void prep_kernel(const float* __restrict__ verts, float4* __restrict__ ws)
{
    const int n = blockIdx.x * 256 + threadIdx.x;    // 0..8191
    const float x = verts[n * 3 + 0];
    const float y = verts[n * 3 + 1];
    const float z = verts[n * 3 + 2];
    ws[n] = make_float4(x, y, z, norm3(x, y, z));
}

extern "C" __global__ __launch_bounds__(THREADS, 4)
void knn_kernel(const float4* __restrict__ ws, int* __restrict__ out)
{
    // Static LDS 62656 B -> 2 blocks/CU, grid 512 = exactly 2/CU.
    __shared__ float4 pts[WIN];                 // 32768 B
    __shared__ float  vdump[NCH][NQB + 1];      // 17408 B
    __shared__ float  hbd[NQB][CAP];            //  4096 B
    __shared__ int    hbi[NQB][CAP];            //  4096 B
    __shared__ int    cand[NQB][MAXC];          //  4096 B
    __shared__ float  Tq[NQB];
    __shared__ int    cnt[NQB];
    __shared__ int    cnt2[NQB];

    const int t    = threadIdx.x;
    const int lane = t & 63;
    const int wv   = t >> 6;          // wave 0..7
    const int c    = t >> 1;          // chunk 0..255
    const int qh   = t & 1;           // query group 0..1
    const int xr   = c & 7;           // read-order stagger (JPW=8)
    const int qbase = blockIdx.x * NQB + qh * QPL;

    if (t < NQB) { cnt[t] = 0; cnt2[t] = 0; }

    // Register tile: 8 queries per lane. Fast path: folded -2*q coords, qn
    // omitted inside the min (constant per query, re-added once).
    float qx2[QPL], qy2[QPL], qz2[QPL], qn[QPL];
#pragma unroll
    for (int i = 0; i < QPL; ++i) {
        const float4 qw = ws[qbase + i];
        qn[i] = qw.w;
        qx2[i] = -2.0f * qw.x; qy2[i] = -2.0f * qw.y; qz2[i] = -2.0f * qw.z;
    }

    // Issue-early / commit-late staging: thread t stages points 4t..4t+3 as
    // 4 aligned float4 (64B/thread); commit is pure ds_write_b128 (no VALU).
    float4 f0, f1, f2, f3;
    auto issue = [&](int w) {
        const float4* vv = ws + w * WIN + 4 * t;
        f0 = vv[0]; f1 = vv[1]; f2 = vv[2]; f3 = vv[3];
    };
    auto commit = [&]() {
        const int m = 4 * t;
        pts[m + 0] = f0; pts[m + 1] = f1; pts[m + 2] = f2; pts[m + 3] = f3;
    };

    // ---------------- PASS 1: per-(chunk,query) MIN (shifted fast dist) -----
    // Chunk c's point set: { w*WIN + c*JPW + j : w in [0,NWIN), j in [0,JPW) }.
    float mn[QPL];
#pragma unroll
    for (int i = 0; i < QPL; ++i) mn[i] = INFINITY;

    issue(0); commit(); __syncthreads();
#pragma unroll 1
    for (int w = 0; w < NWIN; ++w) {
        if (w + 1 < NWIN) issue(w + 1);
#pragma unroll
        for (int v = 0; v < JPW; ++v) {
            const float4 p = pts[c * JPW + (v ^ xr)];
#pragma unroll
            for (int i = 0; i < QPL; ++i) {
                const float d = __builtin_fmaf(p.x, qx2[i],
                                __builtin_fmaf(p.y, qy2[i],
                                __builtin_fmaf(p.z, qz2[i], p.w)));
                mn[i] = fminf(mn[i], d);
            }
        }
        __syncthreads();
        if (w + 1 < NWIN) { commit(); __syncthreads(); }
    }

    // Re-add qn so vdump holds true fast distances.
#pragma unroll
    for (int i = 0; i < QPL; ++i) {
        mn[i] += qn[i];
        vdump[c][qh * QPL + i] = mn[i];
    }
    __syncthreads();

    // ------- T' = 20th smallest of 256 chunk-minima + margin ----------------
    // Wave wv handles queries {2wv, 2wv+1}: 256-elem bitonic, 4 regs/lane
    // (element index = lane*4 + reg; verified R7/R11).
#pragma unroll
    for (int r = 0; r < 2; ++r) {
        const int qq = wv * 2 + r;
        float r0 = vdump[lane * 4 + 0][qq];
        float r1 = vdump[lane * 4 + 1][qq];
        float r2 = vdump[lane * 4 + 2][qq];
        float r3 = vdump[lane * 4 + 3][qq];
        { const float lo = fminf(r0, r1), hi = fmaxf(r0, r1); r0 = lo; r1 = hi; }
        { const float lo = fminf(r2, r3), hi = fmaxf(r2, r3); r2 = hi; r3 = lo; }
#pragma unroll
        for (int k = 4; k <= 256; k <<= 1) {
            const bool asc = (((lane << 2) & k) == 0);
#pragma unroll
            for (int j = k >> 1; j >= 4; j >>= 1) {
                const int lj = j >> 2;
                const bool lower = ((lane & lj) == 0);
                const bool keepmin = (lower == asc);
                const float o0 = __shfl_xor(r0, lj), o1 = __shfl_xor(r1, lj);
                const float o2 = __shfl_xor(r2, lj), o3 = __shfl_xor(r3, lj);
                r0 = keepmin ? fminf(r0, o0) : fmaxf(r0, o0);
                r1 = keepmin ? fminf(r1, o1) : fmaxf(r1, o1);
                r2 = keepmin ? fminf(r2, o2) : fmaxf(r2, o2);
                r3 = keepmin ? fminf(r3, o3) : fmaxf(r3, o3);
            }
            {   // j = 2
                const float lo0 = fminf(r0, r2), hi0 = fmaxf(r0, r2);
                const float lo1 = fminf(r1, r3), hi1 = fmaxf(r1, r3);
                r0 = asc ? lo0 : hi0; r2 = asc ? hi0 : lo0;
                r1 = asc ? lo1 : hi1; r3 = asc ? hi1 : lo1;
            }
            {   // j = 1
                const float lo0 = fminf(r0, r1), hi0 = fmaxf(r0, r1);
                const float lo1 = fminf(r2, r3), hi1 = fmaxf(r2, r3);
                r0 = asc ? lo0 : hi0; r1 = asc ? hi0 : lo0;
                r2 = asc ? lo1 : hi1; r3 = asc ? hi1 : lo1;
            }
        }
        const float T = __shfl(r3, 4);          // element 19 = lane 4, reg 3
        if (lane == 0) Tq[qq] = T + MARGIN;
    }
    __syncthreads();

    // ------- Candidate chunks ------------------------------------------------
#pragma unroll
    for (int i = 0; i < QPL; ++i) {
        const int q = qh * QPL + i;
        if (mn[i] <= Tq[q]) {
            const int e = atomicAdd(&cnt2[q], 1);
            if (e < MAXC) cand[q][e] = c;
        }
    }
    __syncthreads();

    // ------- PASS 2 (sparse, fused 2 queries/wave, 4-deep pipeline) ---------
    // Half-wave = one query: lanes 0-31 -> q=2wv, lanes 32-63 -> q=2wv+1.
    // Point p = lane&31 of chunk cc: n = (p>>3)*WIN + cc*JPW + (p&7);
    // ws[n] is ONE coalesced float4 (norm precomputed).
    {
        const int qq = wv * 2 + (lane >> 5);
        const float4 qw = ws[blockIdx.x * NQB + qq];
        const float T = Tq[qq];
        const int ncq = min(cnt2[qq], MAXC);
        const int ncm = max(min(cnt2[wv * 2], MAXC), min(cnt2[wv * 2 + 1], MAXC));
        const int p = lane & 31;
        const int nfix = (p >> 3) * WIN + (p & 7);
        for (int e0 = 0; e0 < ncm; e0 += 4) {   // wave-uniform groups of 4
            float4 P[4]; int NN[4];
#pragma unroll
            for (int u = 0; u < 4; ++u) {       // 4 coalesced loads in flight
                const int e = e0 + u;
                const int cc = cand[qq][e < ncq ? e : 0];
                const int n = nfix + cc * JPW;
                NN[u] = n;
                P[u] = ws[n];
            }
#pragma unroll
            for (int u = 0; u < 4; ++u) {
                if (e0 + u < ncq) {
                    const float d = dist_exact(P[u].x, P[u].y, P[u].z, P[u].w,
                                               qw.x, qw.y, qw.z, qw.w);
                    if (d <= T) {               // ~25 hits/query total
                        const int slot = atomicAdd(&cnt[qq], 1);
                        if (slot < CAP) { hbd[qq][slot] = d; hbi[qq][slot] = NN[u]; }
                    }
                }
            }
        }
    }
    __syncthreads();

    // ------- Final: exact stable top-20 via u64 bitonic ---------------------
#pragma unroll
    for (int r = 0; r < 2; ++r) {
        const int qq = wv * 2 + r;
        const int kc = min(cnt[qq], CAP);       // kc >= 20 guaranteed
        unsigned long long key = ~0ULL;
        if (lane < kc) {
            const float d = hbd[qq][lane];
            unsigned u = __float_as_uint(d);
            u ^= ((unsigned)((int)u >> 31)) | 0x80000000u;   // order-preserving map
            key = ((unsigned long long)u << 32) | (unsigned)hbi[qq][lane];
        }
#pragma unroll
        for (int k = 2; k <= 64; k <<= 1) {
#pragma unroll
            for (int j = k >> 1; j >= 1; j >>= 1) {
                const unsigned long long o = __shfl_xor(key, j);
                const bool asc = ((lane & k) == 0);
                const bool lower = ((lane & j) == 0);
                const bool keepmin = (lower == asc);
                const bool lt = key < o;
                key = (keepmin == lt) ? key : o;
            }
        }
        if (lane < KK)
            out[(blockIdx.x * NQB + qq) * KK + lane] =
                (int)(unsigned)(key & 0xffffffffULL);
    }
}

extern "C" void kernel_launch(void* const* d_in, const int* in_sizes, int n_in,
                              void* d_out, int out_size, void* d_ws, size_t ws_size,
                              hipStream_t stream) {
    // d_in[0] = feats (unused). d_in[1] = vertices [4,8192,3] f32; batch 0 only.
    const float* verts = (const float*)d_in[1];
    float4* ws = (float4*)d_ws;                 // 8192 * 16 B = 128 KiB scratch
    int* out = (int*)d_out;
    prep_kernel<<<dim3(NPTS / 256), dim3(256), 0, stream>>>(verts, ws);
    knn_kernel<<<dim3(NPTS / NQB), dim3(THREADS), 0, stream>>>(ws, out);
}

// Round 15
// 35.904 us; speedup vs baseline: 2.1805x; 1.0561x over previous
//
#include <hip/hip_runtime.h>
#include <math.h>

#define KK 20
#define NPTS 8192
#define NQB 16              // queries per block
#define QPL 8               // queries per lane (pass 1), as 4 float2 pairs
#define NCH 256             // chunks per query (32 pts each, strided across windows)
#define THREADS 512
#define WIN 2048            // points per staged LDS window
#define NWIN 4
#define JPW (WIN / NCH)     // 8 candidates per chunk per window
#define CAP 64              // hit buffer capacity per query
#define MAXC 64             // candidate-chunk list capacity per query
#define MARGIN 4e-3f        // >> 2*max|d_fast - d_exact|

typedef float v2f __attribute__((ext_vector_type(2)));

// Exact (non-contracted) IEEE ops matching the NumPy reference bit-for-bit.
// np.sum (pairwise, n<8) accumulates ascending: (x^2 + y^2) + z^2.
__device__ __forceinline__ float norm3(float x, float y, float z) {
    return __fadd_rn(__fadd_rn(__fmul_rn(x, x), __fmul_rn(y, y)), __fmul_rn(z, z));
}

// np.einsum (optimize=False) remainder falls through DESCENDING for count=3:
// ((z*z') + y*y') + x*x'.  dist = ((-2*dot) + n_src) + n_dst.
__device__ __forceinline__ float dist_exact(float px, float py, float pz, float pw,
                                            float qx, float qy, float qz, float qn) {
    const float dot = __fadd_rn(
        __fadd_rn(__fmul_rn(pz, qz), __fmul_rn(py, qy)), __fmul_rn(px, qx));
    return __fadd_rn(__fadd_rn(__fmul_rn(dot, -2.0f), pw), qn);
}

extern "C" __global__ __launch_bounds__(THREADS, 4)
void knn_kernel(const float* __restrict__ verts, int* __restrict__ out)
{
    // Static LDS 61888 B -> 2 blocks/CU, grid 512 = exactly 2/CU.
    __shared__ float4 pts[WIN];                 // 32768 B
    __shared__ float  vdump[NQB][NCH + 4];      // 16640 B (transposed, b128 rows)
    __shared__ float  hbd[NQB][CAP];            //  4096 B
    __shared__ int    hbi[NQB][CAP];            //  4096 B
    __shared__ int    cand[NQB][MAXC];          //  4096 B
    __shared__ float  Tq[NQB];
    __shared__ int    cnt[NQB];
    __shared__ int    cnt2[NQB];

    const int t    = threadIdx.x;
    const int lane = t & 63;
    const int wv   = t >> 6;          // wave 0..7
    const int c    = t >> 1;          // chunk 0..255
    const int qh   = t & 1;           // query group 0..1
    const int xr   = c & 7;           // read-order stagger (JPW=8)
    const int qbase = blockIdx.x * NQB + qh * QPL;

    if (t < NQB) { cnt[t] = 0; cnt2[t] = 0; }

    // Register tile: 8 queries per lane as 4 float2 PAIRS (-> v_pk_fma_f32).
    // Fast path: folded -2*q coords, qn omitted inside the min (re-added once).
    v2f qx2[4], qy2[4], qz2[4], qnp[4];
#pragma unroll
    for (int j = 0; j < 4; ++j) {
#pragma unroll
        for (int h = 0; h < 2; ++h) {
            const int qi = qbase + 2 * j + h;
            const float x = verts[qi * 3 + 0];
            const float y = verts[qi * 3 + 1];
            const float z = verts[qi * 3 + 2];
            qnp[j][h] = norm3(x, y, z);
            qx2[j][h] = -2.0f * x; qy2[j][h] = -2.0f * y; qz2[j][h] = -2.0f * z;
        }
    }

    // Issue-early / commit-late staging: thread t stages points 4t..4t+3 of
    // the window as 3x aligned float4 (48 B), norms computed at commit.
    float4 f0, f1, f2;
    auto issue = [&](int w) {
        const float4* vv = (const float4*)verts + (w * (WIN / 4) * 3 + 3 * t);
        f0 = vv[0]; f1 = vv[1]; f2 = vv[2];
    };
    auto commit = [&]() {
        const int m = 4 * t;
        pts[m + 0] = make_float4(f0.x, f0.y, f0.z, norm3(f0.x, f0.y, f0.z));
        pts[m + 1] = make_float4(f0.w, f1.x, f1.y, norm3(f0.w, f1.x, f1.y));
        pts[m + 2] = make_float4(f1.z, f1.w, f2.x, norm3(f1.z, f1.w, f2.x));
        pts[m + 3] = make_float4(f2.y, f2.z, f2.w, norm3(f2.y, f2.z, f2.w));
    };

    // ---------------- PASS 1: per-(chunk,query) MIN (shifted fast dist) -----
    // Chunk c's point set: { w*WIN + c*JPW + j : w in [0,NWIN), j in [0,JPW) }.
    v2f mnp[4];
#pragma unroll
    for (int j = 0; j < 4; ++j) mnp[j] = (v2f){INFINITY, INFINITY};

    issue(0); commit(); __syncthreads();
#pragma unroll 1
    for (int w = 0; w < NWIN; ++w) {
        if (w + 1 < NWIN) issue(w + 1);
#pragma unroll
        for (int v = 0; v < JPW; ++v) {
            const float4 p = pts[c * JPW + (v ^ xr)];
            const v2f sx = {p.x, p.x}, sy = {p.y, p.y},
                      sz = {p.z, p.z}, sw = {p.w, p.w};
#pragma unroll
            for (int j = 0; j < 4; ++j) {
                const v2f d = __builtin_elementwise_fma(sx, qx2[j],
                              __builtin_elementwise_fma(sy, qy2[j],
                              __builtin_elementwise_fma(sz, qz2[j], sw)));
                mnp[j] = __builtin_elementwise_min(mnp[j], d);
            }
        }
        __syncthreads();
        if (w + 1 < NWIN) { commit(); __syncthreads(); }
    }

    // Re-add qn so vdump holds true fast distances; keep scalars for cand test.
    float mns[QPL];
#pragma unroll
    for (int j = 0; j < 4; ++j) {
        mnp[j] += qnp[j];
        mns[2 * j + 0] = mnp[j].x;
        mns[2 * j + 1] = mnp[j].y;
        vdump[qh * QPL + 2 * j + 0][c] = mnp[j].x;
        vdump[qh * QPL + 2 * j + 1][c] = mnp[j].y;
    }
    __syncthreads();

    // ------- T' = 20th smallest of 256 chunk-minima + margin ----------------
    // Wave wv handles queries {2wv, 2wv+1}: 256-elem bitonic, 4 regs/lane
    // (element = lane*4 + reg); one aligned ds_read_b128 per lane.
#pragma unroll
    for (int r = 0; r < 2; ++r) {
        const int qq = wv * 2 + r;
        const float4 vv = *(const float4*)&vdump[qq][lane * 4];
        float r0 = vv.x, r1 = vv.y, r2 = vv.z, r3 = vv.w;
        { const float lo = fminf(r0, r1), hi = fmaxf(r0, r1); r0 = lo; r1 = hi; }
        { const float lo = fminf(r2, r3), hi = fmaxf(r2, r3); r2 = hi; r3 = lo; }
#pragma unroll
        for (int k = 4; k <= 256; k <<= 1) {
            const bool asc = (((lane << 2) & k) == 0);
#pragma unroll
            for (int j = k >> 1; j >= 4; j >>= 1) {
                const int lj = j >> 2;
                const bool lower = ((lane & lj) == 0);
                const bool keepmin = (lower == asc);
                const float o0 = __shfl_xor(r0, lj), o1 = __shfl_xor(r1, lj);
                const float o2 = __shfl_xor(r2, lj), o3 = __shfl_xor(r3, lj);
                r0 = keepmin ? fminf(r0, o0) : fmaxf(r0, o0);
                r1 = keepmin ? fminf(r1, o1) : fmaxf(r1, o1);
                r2 = keepmin ? fminf(r2, o2) : fmaxf(r2, o2);
                r3 = keepmin ? fminf(r3, o3) : fmaxf(r3, o3);
            }
            {   // j = 2
                const float lo0 = fminf(r0, r2), hi0 = fmaxf(r0, r2);
                const float lo1 = fminf(r1, r3), hi1 = fmaxf(r1, r3);
                r0 = asc ? lo0 : hi0; r2 = asc ? hi0 : lo0;
                r1 = asc ? lo1 : hi1; r3 = asc ? hi1 : lo1;
            }
            {   // j = 1
                const float lo0 = fminf(r0, r1), hi0 = fmaxf(r0, r1);
                const float lo1 = fminf(r2, r3), hi1 = fmaxf(r2, r3);
                r0 = asc ? lo0 : hi0; r1 = asc ? hi0 : lo0;
                r2 = asc ? lo1 : hi1; r3 = asc ? hi1 : lo1;
            }
        }
        const float T = __shfl(r3, 4);          // element 19 = lane 4, reg 3
        if (lane == 0) Tq[qq] = T + MARGIN;
    }
    __syncthreads();

    // ------- Candidate chunks ------------------------------------------------
#pragma unroll
    for (int i = 0; i < QPL; ++i) {
        const int q = qh * QPL + i;
        if (mns[i] <= Tq[q]) {
            const int e = atomicAdd(&cnt2[q], 1);
            if (e < MAXC) cand[q][e] = c;
        }
    }
    __syncthreads();

    // ------- PASS 2 (sparse, fused 2 queries/wave, 4-deep pipeline) ---------
    // Half-wave = one query: lanes 0-31 -> q=2wv, lanes 32-63 -> q=2wv+1.
    // Point p = lane&31 of chunk cc: n = (p>>3)*WIN + cc*JPW + (p&7).
    {
        const int qq = wv * 2 + (lane >> 5);
        const int qg2 = blockIdx.x * NQB + qq;
        const float qxe = verts[qg2 * 3 + 0];
        const float qye = verts[qg2 * 3 + 1];
        const float qze = verts[qg2 * 3 + 2];
        const float qne = norm3(qxe, qye, qze);
        const float T = Tq[qq];
        const int ncq = min(cnt2[qq], MAXC);
        const int ncm = max(min(cnt2[wv * 2], MAXC), min(cnt2[wv * 2 + 1], MAXC));
        const int p = lane & 31;
        const int nfix = (p >> 3) * WIN + (p & 7);
        for (int e0 = 0; e0 < ncm; e0 += 4) {   // wave-uniform groups of 4
            float PX[4], PY[4], PZ[4]; int NN[4];
#pragma unroll
            for (int u = 0; u < 4; ++u) {       // 12 independent loads in flight
                const int e = e0 + u;
                const int cc = cand[qq][e < ncq ? e : 0];
                const int n = nfix + cc * JPW;
                NN[u] = n;
                PX[u] = verts[n * 3 + 0];
                PY[u] = verts[n * 3 + 1];
                PZ[u] = verts[n * 3 + 2];
            }
#pragma unroll
            for (int u = 0; u < 4; ++u) {
                if (e0 + u < ncq) {
                    const float pw = norm3(PX[u], PY[u], PZ[u]);
                    const float d = dist_exact(PX[u], PY[u], PZ[u], pw,
                                               qxe, qye, qze, qne);
                    if (d <= T) {               // ~25 hits/query total
                        const int slot = atomicAdd(&cnt[qq], 1);
                        if (slot < CAP) { hbd[qq][slot] = d; hbi[qq][slot] = NN[u]; }
                    }
                }
            }
        }
    }
    __syncthreads();

    // ------- Final: exact stable top-20 via u64 bitonic ---------------------
#pragma unroll
    for (int r = 0; r < 2; ++r) {
        const int qq = wv * 2 + r;
        const int kc = min(cnt[qq], CAP);       // kc >= 20 guaranteed
        unsigned long long key = ~0ULL;
        if (lane < kc) {
            const float d = hbd[qq][lane];
            unsigned u = __float_as_uint(d);
            u ^= ((unsigned)((int)u >> 31)) | 0x80000000u;   // order-preserving map
            key = ((unsigned long long)u << 32) | (unsigned)hbi[qq][lane];
        }
#pragma unroll
        for (int k = 2; k <= 64; k <<= 1) {
#pragma unroll
            for (int j = k >> 1; j >= 1; j >>= 1) {
                const unsigned long long o = __shfl_xor(key, j);
                const bool asc = ((lane & k) == 0);
                const bool lower = ((lane & j) == 0);
                const bool keepmin = (lower == asc);
                const bool lt = key < o;
                key = (keepmin == lt) ? key : o;
            }
        }
        if (lane < KK)
            out[(blockIdx.x * NQB + qq) * KK + lane] =
                (int)(unsigned)(key & 0xffffffffULL);
    }
}

extern "C" void kernel_launch(void* const* d_in, const int* in_sizes, int n_in,
                              void* d_out, int out_size, void* d_ws, size_t ws_size,
                              hipStream_t stream) {
    // d_in[0] = feats (unused). d_in[1] = vertices [4,8192,3] f32; batch 0 only.
    const float* verts = (const float*)d_in[1];
    int* out = (int*)d_out;
    knn_kernel<<<dim3(NPTS / NQB), dim3(THREADS), 0, stream>>>(verts, out);
}

// Round 16
// 32.775 us; speedup vs baseline: 2.3887x; 1.0955x over previous
//
#include <hip/hip_runtime.h>
#include <math.h>

#define KK 20
#define NPTS 8192
#define NQB 16              // queries per block
#define QPL 8               // queries per lane (pass 1)
#define NCH 256             // chunks per query (32 pts each, strided across windows)
#define THREADS 512
#define WIN 2048            // points per staged LDS window
#define NWIN 4
#define JPW (WIN / NCH)     // 8 candidates per chunk per window
#define CAP 64              // hit buffer capacity per query
#define MAXC 64             // candidate-chunk list capacity per query
#define MARGIN 4e-3f        // >> 2*max|d_fast - d_exact|

// Exact (non-contracted) IEEE ops matching the NumPy reference bit-for-bit.
// np.sum (pairwise, n<8) accumulates ascending: (x^2 + y^2) + z^2.
__device__ __forceinline__ float norm3(float x, float y, float z) {
    return __fadd_rn(__fadd_rn(__fmul_rn(x, x), __fmul_rn(y, y)), __fmul_rn(z, z));
}

// np.einsum (optimize=False) remainder falls through DESCENDING for count=3:
// ((z*z') + y*y') + x*x'.  dist = ((-2*dot) + n_src) + n_dst.
__device__ __forceinline__ float dist_exact(float px, float py, float pz, float pw,
                                            float qx, float qy, float qz, float qn) {
    const float dot = __fadd_rn(
        __fadd_rn(__fmul_rn(pz, qz), __fmul_rn(py, qy)), __fmul_rn(px, qx));
    return __fadd_rn(__fadd_rn(__fmul_rn(dot, -2.0f), pw), qn);
}

extern "C" __global__ __launch_bounds__(THREADS, 4)
void knn_kernel(const float* __restrict__ verts, int* __restrict__ out)
{
    // Static LDS 61440 B -> 2 blocks/CU, grid 512 = exactly 2/CU.
    __shared__ float4 pts[WIN];                 // 32768 B
    __shared__ float  vdump[NQB][NCH];          // 16384 B (row per query)
    __shared__ float  hbd[NQB][CAP];            //  4096 B
    __shared__ int    hbi[NQB][CAP];            //  4096 B
    __shared__ int    cand[NQB][MAXC];          //  4096 B

    const int t    = threadIdx.x;
    const int lane = t & 63;
    const int wv   = t >> 6;          // wave 0..7
    const int c    = t >> 1;          // chunk 0..255
    const int qh   = t & 1;           // query group 0..1
    const int xr   = c & 7;           // read-order stagger (JPW=8)
    const int qbase = blockIdx.x * NQB + qh * QPL;

    // Register tile: 8 queries per lane. Fast path: folded -2*q coords, qn
    // omitted inside the min (constant per query, re-added once).
    float qx2[QPL], qy2[QPL], qz2[QPL], qn[QPL];
#pragma unroll
    for (int i = 0; i < QPL; ++i) {
        const float x = verts[(qbase + i) * 3 + 0];
        const float y = verts[(qbase + i) * 3 + 1];
        const float z = verts[(qbase + i) * 3 + 2];
        qn[i] = norm3(x, y, z);
        qx2[i] = -2.0f * x; qy2[i] = -2.0f * y; qz2[i] = -2.0f * z;
    }

    // Issue-early / commit-late staging: thread t stages points 4t..4t+3 of
    // the window as 3x aligned float4 (48 B), norms computed at commit.
    float4 f0, f1, f2;
    auto issue = [&](int w) {
        const float4* vv = (const float4*)verts + (w * (WIN / 4) * 3 + 3 * t);
        f0 = vv[0]; f1 = vv[1]; f2 = vv[2];
    };
    auto commit = [&]() {
        const int m = 4 * t;
        pts[m + 0] = make_float4(f0.x, f0.y, f0.z, norm3(f0.x, f0.y, f0.z));
        pts[m + 1] = make_float4(f0.w, f1.x, f1.y, norm3(f0.w, f1.x, f1.y));
        pts[m + 2] = make_float4(f1.z, f1.w, f2.x, norm3(f1.z, f1.w, f2.x));
        pts[m + 3] = make_float4(f2.y, f2.z, f2.w, norm3(f2.y, f2.z, f2.w));
    };

    // ---------------- PASS 1: per-(chunk,query) MIN (shifted fast dist) -----
    // Chunk c's point set: { w*WIN + c*JPW + j : w in [0,NWIN), j in [0,JPW) }.
    float mn[QPL];
#pragma unroll
    for (int i = 0; i < QPL; ++i) mn[i] = INFINITY;

    issue(0); commit(); __syncthreads();
#pragma unroll 1
    for (int w = 0; w < NWIN; ++w) {
        if (w + 1 < NWIN) issue(w + 1);
#pragma unroll
        for (int v = 0; v < JPW; ++v) {
            const float4 p = pts[c * JPW + (v ^ xr)];
#pragma unroll
            for (int i = 0; i < QPL; ++i) {
                const float d = __builtin_fmaf(p.x, qx2[i],
                                __builtin_fmaf(p.y, qy2[i],
                                __builtin_fmaf(p.z, qz2[i], p.w)));
                mn[i] = fminf(mn[i], d);
            }
        }
        __syncthreads();
        if (w + 1 < NWIN) { commit(); __syncthreads(); }
    }

    // Re-add qn so vdump holds true fast distances (row per query).
#pragma unroll
    for (int i = 0; i < QPL; ++i) {
        mn[i] += qn[i];
        vdump[qh * QPL + i][c] = mn[i];
    }
    __syncthreads();
    // -------- From here on, EVERYTHING is wave-local (no barriers/atomics). --
    // Wave wv owns queries {2wv, 2wv+1}.

    float Tr[2]; int ncr[2];
#pragma unroll
    for (int r = 0; r < 2; ++r) {
        const int qq = wv * 2 + r;
        // One aligned b128 per lane: elements lane*4 .. lane*4+3 of query row.
        const float4 sv = *(const float4*)&vdump[qq][lane * 4];

        // ---- T' = 20th smallest of 256 chunk-minima (bitonic, 4 regs/lane) --
        float r0 = sv.x, r1 = sv.y, r2 = sv.z, r3 = sv.w;
        { const float lo = fminf(r0, r1), hi = fmaxf(r0, r1); r0 = lo; r1 = hi; }
        { const float lo = fminf(r2, r3), hi = fmaxf(r2, r3); r2 = hi; r3 = lo; }
#pragma unroll
        for (int k = 4; k <= 256; k <<= 1) {
            const bool asc = (((lane << 2) & k) == 0);
#pragma unroll
            for (int j = k >> 1; j >= 4; j >>= 1) {
                const int lj = j >> 2;
                const bool lower = ((lane & lj) == 0);
                const bool keepmin = (lower == asc);
                const float o0 = __shfl_xor(r0, lj), o1 = __shfl_xor(r1, lj);
                const float o2 = __shfl_xor(r2, lj), o3 = __shfl_xor(r3, lj);
                r0 = keepmin ? fminf(r0, o0) : fmaxf(r0, o0);
                r1 = keepmin ? fminf(r1, o1) : fmaxf(r1, o1);
                r2 = keepmin ? fminf(r2, o2) : fmaxf(r2, o2);
                r3 = keepmin ? fminf(r3, o3) : fmaxf(r3, o3);
            }
            {   // j = 2
                const float lo0 = fminf(r0, r2), hi0 = fmaxf(r0, r2);
                const float lo1 = fminf(r1, r3), hi1 = fmaxf(r1, r3);
                r0 = asc ? lo0 : hi0; r2 = asc ? hi0 : lo0;
                r1 = asc ? lo1 : hi1; r3 = asc ? hi1 : lo1;
            }
            {   // j = 1
                const float lo0 = fminf(r0, r1), hi0 = fmaxf(r0, r1);
                const float lo1 = fminf(r2, r3), hi1 = fmaxf(r2, r3);
                r0 = asc ? lo0 : hi0; r1 = asc ? hi0 : lo0;
                r2 = asc ? lo1 : hi1; r3 = asc ? hi1 : lo1;
            }
        }
        const float T = __shfl(r3, 4) + MARGIN; // element 19 = lane 4, reg 3
        Tr[r] = T;

        // ---- Candidate chunks via ballot compaction (no atomics) -----------
        const unsigned long long b0 = __ballot(sv.x <= T);
        const unsigned long long b1 = __ballot(sv.y <= T);
        const unsigned long long b2 = __ballot(sv.z <= T);
        const unsigned long long b3 = __ballot(sv.w <= T);
        const int c0 = __popcll(b0), c1 = __popcll(b1), c2 = __popcll(b2);
        const unsigned long long below = (1ULL << lane) - 1;
        const int k0 = __popcll(b0 & below);
        const int k1 = c0 + __popcll(b1 & below);
        const int k2 = c0 + c1 + __popcll(b2 & below);
        const int k3 = c0 + c1 + c2 + __popcll(b3 & below);
        if ((sv.x <= T) && k0 < MAXC) cand[qq][k0] = lane * 4 + 0;
        if ((sv.y <= T) && k1 < MAXC) cand[qq][k1] = lane * 4 + 1;
        if ((sv.z <= T) && k2 < MAXC) cand[qq][k2] = lane * 4 + 2;
        if ((sv.w <= T) && k3 < MAXC) cand[qq][k3] = lane * 4 + 3;
        ncr[r] = min(c0 + c1 + c2 + __popcll(b3), MAXC);
    }

    // ------- PASS 2 (sparse, fused 2 queries/wave, 4-deep pipeline) ---------
    // Half-wave = one query: lanes 0-31 -> q=2wv, lanes 32-63 -> q=2wv+1.
    // Point p = lane&31 of chunk cc: n = (p>>3)*WIN + cc*JPW + (p&7).
    int hc0 = 0, hc1 = 0;                       // per-query hit counts (uniform)
    {
        const int qq = wv * 2 + (lane >> 5);
        const int qg2 = blockIdx.x * NQB + qq;
        const float qxe = verts[qg2 * 3 + 0];
        const float qye = verts[qg2 * 3 + 1];
        const float qze = verts[qg2 * 3 + 2];
        const float qne = norm3(qxe, qye, qze);
        const float T = (lane < 32) ? Tr[0] : Tr[1];
        const int ncq = (lane < 32) ? ncr[0] : ncr[1];
        const int ncm = max(ncr[0], ncr[1]);
        const int p = lane & 31;
        const int nfix = (p >> 3) * WIN + (p & 7);
        for (int e0 = 0; e0 < ncm; e0 += 4) {   // wave-uniform groups of 4
            float PX[4], PY[4], PZ[4]; int NN[4];
#pragma unroll
            for (int u = 0; u < 4; ++u) {       // 12 independent loads in flight
                const int e = e0 + u;
                const int cc = cand[qq][e < ncq ? e : 0];
                const int n = nfix + cc * JPW;
                NN[u] = n;
                PX[u] = verts[n * 3 + 0];
                PY[u] = verts[n * 3 + 1];
                PZ[u] = verts[n * 3 + 2];
            }
#pragma unroll
            for (int u = 0; u < 4; ++u) {
                const float pw = norm3(PX[u], PY[u], PZ[u]);
                const float d = dist_exact(PX[u], PY[u], PZ[u], pw,
                                           qxe, qye, qze, qne);
                const bool pred = ((e0 + u) < ncq) && (d <= T);
                // Ballot-compacted hit append (no atomics).
                const unsigned long long bal = __ballot(pred);
                const int lc = __popcll(bal & 0xFFFFFFFFULL);
                const int hcv = __popcll(bal >> 32);
                const int base = (lane < 32) ? hc0 : hc1;
                const unsigned long long below = bal & ((1ULL << lane) - 1);
                const int rank = (lane < 32) ? __popcll(below)
                                             : __popcll(below >> 32);
                if (pred) {
                    const int slot = base + rank;
                    if (slot < CAP) { hbd[qq][slot] = d; hbi[qq][slot] = NN[u]; }
                }
                hc0 += lc; hc1 += hcv;
            }
        }
    }

    // ------- Final: exact stable top-20 via u64 bitonic ---------------------
#pragma unroll
    for (int r = 0; r < 2; ++r) {
        const int qq = wv * 2 + r;
        const int kc = min((r == 0) ? hc0 : hc1, CAP);   // kc >= 20 guaranteed
        unsigned long long key = ~0ULL;
        if (lane < kc) {
            const float d = hbd[qq][lane];
            unsigned u = __float_as_uint(d);
            u ^= ((unsigned)((int)u >> 31)) | 0x80000000u;   // order-preserving map
            key = ((unsigned long long)u << 32) | (unsigned)hbi[qq][lane];
        }
#pragma unroll
        for (int k = 2; k <= 64; k <<= 1) {
#pragma unroll
            for (int j = k >> 1; j >= 1; j >>= 1) {
                const unsigned long long o = __shfl_xor(key, j);
                const bool asc = ((lane & k) == 0);
                const bool lower = ((lane & j) == 0);
                const bool keepmin = (lower == asc);
                const bool lt = key < o;
                key = (keepmin == lt) ? key : o;
            }
        }
        if (lane < KK)
            out[(blockIdx.x * NQB + qq) * KK + lane] =
                (int)(unsigned)(key & 0xffffffffULL);
    }
}

extern "C" void kernel_launch(void* const* d_in, const int* in_sizes, int n_in,
                              void* d_out, int out_size, void* d_ws, size_t ws_size,
                              hipStream_t stream) {
    // d_in[0] = feats (unused). d_in[1] = vertices [4,8192,3] f32; batch 0 only.
    const float* verts = (const float*)d_in[1];
    int* out = (int*)d_out;
    knn_kernel<<<dim3(NPTS / NQB), dim3(THREADS), 0, stream>>>(verts, out);
}

// Round 17
// 32.003 us; speedup vs baseline: 2.4463x; 1.0241x over previous
//
#include <hip/hip_runtime.h>
#include <math.h>

#define KK 20
#define NPTS 8192
#define NQB 16              // queries per block
#define QPL 8               // queries per lane (pass 1)
#define NCH 256             // chunks per query (32 pts: 4 windows x 8 consecutive)
#define THREADS 512
#define WIN 2048
#define NWIN 4
#define JPW 8               // consecutive points per chunk per window
#define CAP 64              // hit buffer capacity per query
#define MAXC 64             // candidate-chunk list capacity per query
#define MARGIN 4e-3f        // >> 2*max|d_fast - d_exact|

// Exact (non-contracted) IEEE ops matching the NumPy reference bit-for-bit.
// np.sum (pairwise, n<8) accumulates ascending: (x^2 + y^2) + z^2.
__device__ __forceinline__ float norm3(float x, float y, float z) {
    return __fadd_rn(__fadd_rn(__fmul_rn(x, x), __fmul_rn(y, y)), __fmul_rn(z, z));
}

// np.einsum (optimize=False) remainder falls through DESCENDING for count=3:
// ((z*z') + y*y') + x*x'.  dist = ((-2*dot) + n_src) + n_dst.
__device__ __forceinline__ float dist_exact(float px, float py, float pz, float pw,
                                            float qx, float qy, float qz, float qn) {
    const float dot = __fadd_rn(
        __fadd_rn(__fmul_rn(pz, qz), __fmul_rn(py, qy)), __fmul_rn(px, qx));
    return __fadd_rn(__fadd_rn(__fmul_rn(dot, -2.0f), pw), qn);
}

extern "C" __global__ __launch_bounds__(THREADS, 4)
void knn_kernel(const float* __restrict__ verts, int* __restrict__ out)
{
    // Static LDS 28672 B. Grid 512 = 2 blocks/CU.
    __shared__ float  vdump[NQB][NCH];          // 16384 B (row per query)
    __shared__ float  hbd[NQB][CAP];            //  4096 B
    __shared__ int    hbi[NQB][CAP];            //  4096 B
    __shared__ int    cand[NQB][MAXC];          //  4096 B

    const int t    = threadIdx.x;
    const int lane = t & 63;
    const int wv   = t >> 6;          // wave 0..7
    const int c    = t >> 1;          // chunk 0..255
    const int qh   = t & 1;           // query group 0..1
    const int qbase = blockIdx.x * NQB + qh * QPL;

    // Register tile: 8 queries per lane. Fast path: folded -2*q coords, qn
    // omitted inside the min (constant per query, re-added once).
    float qx2[QPL], qy2[QPL], qz2[QPL], qn[QPL];
#pragma unroll
    for (int i = 0; i < QPL; ++i) {
        const float x = verts[(qbase + i) * 3 + 0];
        const float y = verts[(qbase + i) * 3 + 1];
        const float z = verts[(qbase + i) * 3 + 2];
        qn[i] = norm3(x, y, z);
        qx2[i] = -2.0f * x; qy2[i] = -2.0f * y; qz2[i] = -2.0f * z;
    }

    // ---------------- PASS 1: per-(chunk,query) MIN, straight from global ---
    // Chunk c's point set: { w*WIN + c*JPW + j : w<4, j<8 }. Per window the
    // chunk is 24 consecutive floats = 6 aligned float4 ((w*2048+c*8)*12 B is
    // 96B-aligned). Thread pairs (c = t>>1) read identical lines -> L1 serves.
    // NO barriers, NO LDS in this phase: waves fully decoupled.
    float mn[QPL];
#pragma unroll
    for (int i = 0; i < QPL; ++i) mn[i] = INFINITY;

    auto pair8 = [&](float px, float py, float pz) {
        const float pw = norm3(px, py, pz);
#pragma unroll
        for (int i = 0; i < QPL; ++i) {
            const float d = __builtin_fmaf(px, qx2[i],
                            __builtin_fmaf(py, qy2[i],
                            __builtin_fmaf(pz, qz2[i], pw)));
            mn[i] = fminf(mn[i], d);
        }
    };

#pragma unroll
    for (int w = 0; w < NWIN; ++w) {
        const float4* vp = (const float4*)(verts + (w * WIN + c * JPW) * 3);
        const float4 A = vp[0], B = vp[1], C = vp[2];
        const float4 D = vp[3], E = vp[4], F = vp[5];
        pair8(A.x, A.y, A.z); pair8(A.w, B.x, B.y);
        pair8(B.z, B.w, C.x); pair8(C.y, C.z, C.w);
        pair8(D.x, D.y, D.z); pair8(D.w, E.x, E.y);
        pair8(E.z, E.w, F.x); pair8(F.y, F.z, F.w);
    }

    // Re-add qn so vdump holds true fast distances (row per query).
#pragma unroll
    for (int i = 0; i < QPL; ++i) {
        mn[i] += qn[i];
        vdump[qh * QPL + i][c] = mn[i];
    }
    __syncthreads();
    // -------- From here on, EVERYTHING is wave-local (no barriers/atomics). --
    // Wave wv owns queries {2wv, 2wv+1}.

    float Tr[2]; int ncr[2];
#pragma unroll
    for (int r = 0; r < 2; ++r) {
        const int qq = wv * 2 + r;
        // One aligned b128 per lane: elements lane*4 .. lane*4+3 of query row.
        const float4 sv = *(const float4*)&vdump[qq][lane * 4];

        // ---- T' = 20th smallest of 256 chunk-minima (bitonic, 4 regs/lane) --
        float r0 = sv.x, r1 = sv.y, r2 = sv.z, r3 = sv.w;
        { const float lo = fminf(r0, r1), hi = fmaxf(r0, r1); r0 = lo; r1 = hi; }
        { const float lo = fminf(r2, r3), hi = fmaxf(r2, r3); r2 = hi; r3 = lo; }
#pragma unroll
        for (int k = 4; k <= 256; k <<= 1) {
            const bool asc = (((lane << 2) & k) == 0);
#pragma unroll
            for (int j = k >> 1; j >= 4; j >>= 1) {
                const int lj = j >> 2;
                const bool lower = ((lane & lj) == 0);
                const bool keepmin = (lower == asc);
                const float o0 = __shfl_xor(r0, lj), o1 = __shfl_xor(r1, lj);
                const float o2 = __shfl_xor(r2, lj), o3 = __shfl_xor(r3, lj);
                r0 = keepmin ? fminf(r0, o0) : fmaxf(r0, o0);
                r1 = keepmin ? fminf(r1, o1) : fmaxf(r1, o1);
                r2 = keepmin ? fminf(r2, o2) : fmaxf(r2, o2);
                r3 = keepmin ? fminf(r3, o3) : fmaxf(r3, o3);
            }
            {   // j = 2
                const float lo0 = fminf(r0, r2), hi0 = fmaxf(r0, r2);
                const float lo1 = fminf(r1, r3), hi1 = fmaxf(r1, r3);
                r0 = asc ? lo0 : hi0; r2 = asc ? hi0 : lo0;
                r1 = asc ? lo1 : hi1; r3 = asc ? hi1 : lo1;
            }
            {   // j = 1
                const float lo0 = fminf(r0, r1), hi0 = fmaxf(r0, r1);
                const float lo1 = fminf(r2, r3), hi1 = fmaxf(r2, r3);
                r0 = asc ? lo0 : hi0; r1 = asc ? hi0 : lo0;
                r2 = asc ? lo1 : hi1; r3 = asc ? hi1 : lo1;
            }
        }
        const float T = __shfl(r3, 4) + MARGIN; // element 19 = lane 4, reg 3
        Tr[r] = T;

        // ---- Candidate chunks via ballot compaction (no atomics) -----------
        const unsigned long long b0 = __ballot(sv.x <= T);
        const unsigned long long b1 = __ballot(sv.y <= T);
        const unsigned long long b2 = __ballot(sv.z <= T);
        const unsigned long long b3 = __ballot(sv.w <= T);
        const int c0 = __popcll(b0), c1 = __popcll(b1), c2 = __popcll(b2);
        const unsigned long long below = (1ULL << lane) - 1;
        const int k0 = __popcll(b0 & below);
        const int k1 = c0 + __popcll(b1 & below);
        const int k2 = c0 + c1 + __popcll(b2 & below);
        const int k3 = c0 + c1 + c2 + __popcll(b3 & below);
        if ((sv.x <= T) && k0 < MAXC) cand[qq][k0] = lane * 4 + 0;
        if ((sv.y <= T) && k1 < MAXC) cand[qq][k1] = lane * 4 + 1;
        if ((sv.z <= T) && k2 < MAXC) cand[qq][k2] = lane * 4 + 2;
        if ((sv.w <= T) && k3 < MAXC) cand[qq][k3] = lane * 4 + 3;
        ncr[r] = min(c0 + c1 + c2 + __popcll(b3), MAXC);
    }

    // ------- PASS 2 (sparse, fused 2 queries/wave, 4-deep pipeline) ---------
    // Half-wave = one query: lanes 0-31 -> q=2wv, lanes 32-63 -> q=2wv+1.
    // Point p = lane&31 of chunk cc: n = (p>>3)*WIN + cc*JPW + (p&7).
    int hc0 = 0, hc1 = 0;                       // per-query hit counts (uniform)
    {
        const int qq = wv * 2 + (lane >> 5);
        const int qg2 = blockIdx.x * NQB + qq;
        const float qxe = verts[qg2 * 3 + 0];
        const float qye = verts[qg2 * 3 + 1];
        const float qze = verts[qg2 * 3 + 2];
        const float qne = norm3(qxe, qye, qze);
        const float T = (lane < 32) ? Tr[0] : Tr[1];
        const int ncq = (lane < 32) ? ncr[0] : ncr[1];
        const int ncm = max(ncr[0], ncr[1]);
        const int p = lane & 31;
        const int nfix = (p >> 3) * WIN + (p & 7);
        for (int e0 = 0; e0 < ncm; e0 += 4) {   // wave-uniform groups of 4
            float PX[4], PY[4], PZ[4]; int NN[4];
#pragma unroll
            for (int u = 0; u < 4; ++u) {       // 12 independent loads in flight
                const int e = e0 + u;
                const int cc = cand[qq][e < ncq ? e : 0];
                const int n = nfix + cc * JPW;
                NN[u] = n;
                PX[u] = verts[n * 3 + 0];
                PY[u] = verts[n * 3 + 1];
                PZ[u] = verts[n * 3 + 2];
            }
#pragma unroll
            for (int u = 0; u < 4; ++u) {
                const float pw = norm3(PX[u], PY[u], PZ[u]);
                const float d = dist_exact(PX[u], PY[u], PZ[u], pw,
                                           qxe, qye, qze, qne);
                const bool pred = ((e0 + u) < ncq) && (d <= T);
                // Ballot-compacted hit append (no atomics).
                const unsigned long long bal = __ballot(pred);
                const int lc = __popcll(bal & 0xFFFFFFFFULL);
                const int hcv = __popcll(bal >> 32);
                const int base = (lane < 32) ? hc0 : hc1;
                const unsigned long long blw = bal & ((1ULL << lane) - 1);
                const int rank = (lane < 32) ? __popcll(blw)
                                             : __popcll(blw >> 32);
                if (pred) {
                    const int slot = base + rank;
                    if (slot < CAP) { hbd[qq][slot] = d; hbi[qq][slot] = NN[u]; }
                }
                hc0 += lc; hc1 += hcv;
            }
        }
    }

    // ------- Final: exact stable top-20 via u64 bitonic ---------------------
#pragma unroll
    for (int r = 0; r < 2; ++r) {
        const int qq = wv * 2 + r;
        const int kc = min((r == 0) ? hc0 : hc1, CAP);   // kc >= 20 guaranteed
        unsigned long long key = ~0ULL;
        if (lane < kc) {
            const float d = hbd[qq][lane];
            unsigned u = __float_as_uint(d);
            u ^= ((unsigned)((int)u >> 31)) | 0x80000000u;   // order-preserving map
            key = ((unsigned long long)u << 32) | (unsigned)hbi[qq][lane];
        }
#pragma unroll
        for (int k = 2; k <= 64; k <<= 1) {
#pragma unroll
            for (int j = k >> 1; j >= 1; j >>= 1) {
                const unsigned long long o = __shfl_xor(key, j);
                const bool asc = ((lane & k) == 0);
                const bool lower = ((lane & j) == 0);
                const bool keepmin = (lower == asc);
                const bool lt = key < o;
                key = (keepmin == lt) ? key : o;
            }
        }
        if (lane < KK)
            out[(blockIdx.x * NQB + qq) * KK + lane] =
                (int)(unsigned)(key & 0xffffffffULL);
    }
}

extern "C" void kernel_launch(void* const* d_in, const int* in_sizes, int n_in,
                              void* d_out, int out_size, void* d_ws, size_t ws_size,
                              hipStream_t stream) {
    // d_in[0] = feats (unused). d_in[1] = vertices [4,8192,3] f32; batch 0 only.
    const float* verts = (const float*)d_in[1];
    int* out = (int*)d_out;
    knn_kernel<<<dim3(NPTS / NQB), dim3(THREADS), 0, stream>>>(verts, out);
}

// Round 18
// 31.695 us; speedup vs baseline: 2.4700x; 1.0097x over previous
//
#include <hip/hip_runtime.h>
#include <math.h>

#define KK 20
#define NPTS 8192
#define NQB 8               // queries per block
#define QPL 8               // queries per lane (pass 1)
#define NCH 256             // chunks per query (32 pts: 4 windows x 8 consecutive)
#define THREADS 256
#define WIN 2048
#define NWIN 4
#define JPW 8               // consecutive points per chunk per window
#define CAP 64              // hit buffer capacity per query
#define MAXC 64             // candidate-chunk list capacity per query
#define MARGIN 4e-3f        // >> 2*max|d_fast - d_exact|

// Exact (non-contracted) IEEE ops matching the NumPy reference bit-for-bit.
// np.sum (pairwise, n<8) accumulates ascending: (x^2 + y^2) + z^2.
__device__ __forceinline__ float norm3(float x, float y, float z) {
    return __fadd_rn(__fadd_rn(__fmul_rn(x, x), __fmul_rn(y, y)), __fmul_rn(z, z));
}

// np.einsum (optimize=False) remainder falls through DESCENDING for count=3:
// ((z*z') + y*y') + x*x'.  dist = ((-2*dot) + n_src) + n_dst.
__device__ __forceinline__ float dist_exact(float px, float py, float pz, float pw,
                                            float qx, float qy, float qz, float qn) {
    const float dot = __fadd_rn(
        __fadd_rn(__fmul_rn(pz, qz), __fmul_rn(py, qy)), __fmul_rn(px, qx));
    return __fadd_rn(__fadd_rn(__fmul_rn(dot, -2.0f), pw), qn);
}

extern "C" __global__ __launch_bounds__(THREADS, 4)
void knn_kernel(const float* __restrict__ verts, int* __restrict__ out)
{
    // Static LDS 14336 B. Grid 1024 = 4 blocks/CU (VGPR-capped residency).
    __shared__ float  vdump[NQB][NCH];          // 8192 B (row per query)
    __shared__ float  hbd[NQB][CAP];            // 2048 B
    __shared__ int    hbi[NQB][CAP];            // 2048 B
    __shared__ int    cand[NQB][MAXC];          // 2048 B

    const int t    = threadIdx.x;
    const int lane = t & 63;
    const int wv   = t >> 6;          // wave 0..3
    const int c    = t;               // chunk 0..255 (one per thread)
    const int qbase = blockIdx.x * NQB;

    // Register tile: all 8 block queries per lane. Fast path: folded -2*q
    // coords, qn omitted inside the min (constant per query, re-added once).
    float qx2[QPL], qy2[QPL], qz2[QPL], qn[QPL];
#pragma unroll
    for (int i = 0; i < QPL; ++i) {
        const float x = verts[(qbase + i) * 3 + 0];
        const float y = verts[(qbase + i) * 3 + 1];
        const float z = verts[(qbase + i) * 3 + 2];
        qn[i] = norm3(x, y, z);
        qx2[i] = -2.0f * x; qy2[i] = -2.0f * y; qz2[i] = -2.0f * z;
    }

    // ---------------- PASS 1: per-(chunk,query) MIN, straight from global ---
    // Chunk c's point set: { w*WIN + c*JPW + j : w<4, j<8 }. Per window the
    // chunk is 24 consecutive floats = 6 aligned float4 (96B-aligned base).
    // NO barriers, NO LDS in this phase: waves fully decoupled.
    float mn[QPL];
#pragma unroll
    for (int i = 0; i < QPL; ++i) mn[i] = INFINITY;

    auto pair8 = [&](float px, float py, float pz) {
        const float pw = norm3(px, py, pz);
#pragma unroll
        for (int i = 0; i < QPL; ++i) {
            const float d = __builtin_fmaf(px, qx2[i],
                            __builtin_fmaf(py, qy2[i],
                            __builtin_fmaf(pz, qz2[i], pw)));
            mn[i] = fminf(mn[i], d);
        }
    };

#pragma unroll
    for (int w = 0; w < NWIN; ++w) {
        const float4* vp = (const float4*)(verts + (w * WIN + c * JPW) * 3);
        const float4 A = vp[0], B = vp[1], C = vp[2];
        const float4 D = vp[3], E = vp[4], F = vp[5];
        pair8(A.x, A.y, A.z); pair8(A.w, B.x, B.y);
        pair8(B.z, B.w, C.x); pair8(C.y, C.z, C.w);
        pair8(D.x, D.y, D.z); pair8(D.w, E.x, E.y);
        pair8(E.z, E.w, F.x); pair8(F.y, F.z, F.w);
    }

    // Re-add qn so vdump holds true fast distances (row per query).
#pragma unroll
    for (int i = 0; i < QPL; ++i) {
        mn[i] += qn[i];
        vdump[i][c] = mn[i];
    }
    __syncthreads();
    // -------- From here on, EVERYTHING is wave-local (no barriers/atomics). --
    // Wave wv owns queries {2wv, 2wv+1}.

    float Tr[2]; int ncr[2];
#pragma unroll
    for (int r = 0; r < 2; ++r) {
        const int qq = wv * 2 + r;
        // One aligned b128 per lane: elements lane*4 .. lane*4+3 of query row.
        const float4 sv = *(const float4*)&vdump[qq][lane * 4];

        // ---- T' = 20th smallest of 256 chunk-minima (bitonic, 4 regs/lane) --
        float r0 = sv.x, r1 = sv.y, r2 = sv.z, r3 = sv.w;
        { const float lo = fminf(r0, r1), hi = fmaxf(r0, r1); r0 = lo; r1 = hi; }
        { const float lo = fminf(r2, r3), hi = fmaxf(r2, r3); r2 = hi; r3 = lo; }
#pragma unroll
        for (int k = 4; k <= 256; k <<= 1) {
            const bool asc = (((lane << 2) & k) == 0);
#pragma unroll
            for (int j = k >> 1; j >= 4; j >>= 1) {
                const int lj = j >> 2;
                const bool lower = ((lane & lj) == 0);
                const bool keepmin = (lower == asc);
                const float o0 = __shfl_xor(r0, lj), o1 = __shfl_xor(r1, lj);
                const float o2 = __shfl_xor(r2, lj), o3 = __shfl_xor(r3, lj);
                r0 = keepmin ? fminf(r0, o0) : fmaxf(r0, o0);
                r1 = keepmin ? fminf(r1, o1) : fmaxf(r1, o1);
                r2 = keepmin ? fminf(r2, o2) : fmaxf(r2, o2);
                r3 = keepmin ? fminf(r3, o3) : fmaxf(r3, o3);
            }
            {   // j = 2
                const float lo0 = fminf(r0, r2), hi0 = fmaxf(r0, r2);
                const float lo1 = fminf(r1, r3), hi1 = fmaxf(r1, r3);
                r0 = asc ? lo0 : hi0; r2 = asc ? hi0 : lo0;
                r1 = asc ? lo1 : hi1; r3 = asc ? hi1 : lo1;
            }
            {   // j = 1
                const float lo0 = fminf(r0, r1), hi0 = fmaxf(r0, r1);
                const float lo1 = fminf(r2, r3), hi1 = fmaxf(r2, r3);
                r0 = asc ? lo0 : hi0; r1 = asc ? hi0 : lo0;
                r2 = asc ? lo1 : hi1; r3 = asc ? hi1 : lo1;
            }
        }
        const float T = __shfl(r3, 4) + MARGIN; // element 19 = lane 4, reg 3
        Tr[r] = T;

        // ---- Candidate chunks via ballot compaction (no atomics) -----------
        const unsigned long long b0 = __ballot(sv.x <= T);
        const unsigned long long b1 = __ballot(sv.y <= T);
        const unsigned long long b2 = __ballot(sv.z <= T);
        const unsigned long long b3 = __ballot(sv.w <= T);
        const int c0 = __popcll(b0), c1 = __popcll(b1), c2 = __popcll(b2);
        const unsigned long long below = (1ULL << lane) - 1;
        const int k0 = __popcll(b0 & below);
        const int k1 = c0 + __popcll(b1 & below);
        const int k2 = c0 + c1 + __popcll(b2 & below);
        const int k3 = c0 + c1 + c2 + __popcll(b3 & below);
        if ((sv.x <= T) && k0 < MAXC) cand[qq][k0] = lane * 4 + 0;
        if ((sv.y <= T) && k1 < MAXC) cand[qq][k1] = lane * 4 + 1;
        if ((sv.z <= T) && k2 < MAXC) cand[qq][k2] = lane * 4 + 2;
        if ((sv.w <= T) && k3 < MAXC) cand[qq][k3] = lane * 4 + 3;
        ncr[r] = min(c0 + c1 + c2 + __popcll(b3), MAXC);
    }

    // ------- PASS 2 (sparse, fused 2 queries/wave, 4-deep pipeline) ---------
    // Half-wave = one query: lanes 0-31 -> q=2wv, lanes 32-63 -> q=2wv+1.
    // Point p = lane&31 of chunk cc: n = (p>>3)*WIN + cc*JPW + (p&7).
    int hc0 = 0, hc1 = 0;                       // per-query hit counts (uniform)
    {
        const int qq = wv * 2 + (lane >> 5);
        const int qg2 = blockIdx.x * NQB + qq;
        const float qxe = verts[qg2 * 3 + 0];
        const float qye = verts[qg2 * 3 + 1];
        const float qze = verts[qg2 * 3 + 2];
        const float qne = norm3(qxe, qye, qze);
        const float T = (lane < 32) ? Tr[0] : Tr[1];
        const int ncq = (lane < 32) ? ncr[0] : ncr[1];
        const int ncm = max(ncr[0], ncr[1]);
        const int p = lane & 31;
        const int nfix = (p >> 3) * WIN + (p & 7);
        for (int e0 = 0; e0 < ncm; e0 += 4) {   // wave-uniform groups of 4
            float PX[4], PY[4], PZ[4]; int NN[4];
#pragma unroll
            for (int u = 0; u < 4; ++u) {       // 12 independent loads in flight
                const int e = e0 + u;
                const int cc = cand[qq][e < ncq ? e : 0];
                const int n = nfix + cc * JPW;
                NN[u] = n;
                PX[u] = verts[n * 3 + 0];
                PY[u] = verts[n * 3 + 1];
                PZ[u] = verts[n * 3 + 2];
            }
#pragma unroll
            for (int u = 0; u < 4; ++u) {
                const float pw = norm3(PX[u], PY[u], PZ[u]);
                const float d = dist_exact(PX[u], PY[u], PZ[u], pw,
                                           qxe, qye, qze, qne);
                const bool pred = ((e0 + u) < ncq) && (d <= T);
                // Ballot-compacted hit append (no atomics).
                const unsigned long long bal = __ballot(pred);
                const int lc = __popcll(bal & 0xFFFFFFFFULL);
                const int hcv = __popcll(bal >> 32);
                const int base = (lane < 32) ? hc0 : hc1;
                const unsigned long long blw = bal & ((1ULL << lane) - 1);
                const int rank = (lane < 32) ? __popcll(blw)
                                             : __popcll(blw >> 32);
                if (pred) {
                    const int slot = base + rank;
                    if (slot < CAP) { hbd[qq][slot] = d; hbi[qq][slot] = NN[u]; }
                }
                hc0 += lc; hc1 += hcv;
            }
        }
    }

    // ------- Final: exact stable top-20 via u64 bitonic ---------------------
#pragma unroll
    for (int r = 0; r < 2; ++r) {
        const int qq = wv * 2 + r;
        const int kc = min((r == 0) ? hc0 : hc1, CAP);   // kc >= 20 guaranteed
        unsigned long long key = ~0ULL;
        if (lane < kc) {
            const float d = hbd[qq][lane];
            unsigned u = __float_as_uint(d);
            u ^= ((unsigned)((int)u >> 31)) | 0x80000000u;   // order-preserving map
            key = ((unsigned long long)u << 32) | (unsigned)hbi[qq][lane];
        }
#pragma unroll
        for (int k = 2; k <= 64; k <<= 1) {
#pragma unroll
            for (int j = k >> 1; j >= 1; j >>= 1) {
                const unsigned long long o = __shfl_xor(key, j);
                const bool asc = ((lane & k) == 0);
                const bool lower = ((lane & j) == 0);
                const bool keepmin = (lower == asc);
                const bool lt = key < o;
                key = (keepmin == lt) ? key : o;
            }
        }
        if (lane < KK)
            out[(blockIdx.x * NQB + qq) * KK + lane] =
                (int)(unsigned)(key & 0xffffffffULL);
    }
}

extern "C" void kernel_launch(void* const* d_in, const int* in_sizes, int n_in,
                              void* d_out, int out_size, void* d_ws, size_t ws_size,
                              hipStream_t stream) {
    // d_in[0] = feats (unused). d_in[1] = vertices [4,8192,3] f32; batch 0 only.
    const float* verts = (const float*)d_in[1];
    int* out = (int*)d_out;
    knn_kernel<<<dim3(NPTS / NQB), dim3(THREADS), 0, stream>>>(verts, out);
}